// Round 1
// baseline (148.312 us; speedup 1.0000x reference)
//
#include <hip/hip_runtime.h>
#include <hip/hip_bf16.h>

#define KDIM 1024
#define NDIM 1024
#define NEXP 8
#define TTOK 8192
#define NT (KDIM / 32)

typedef __bf16 bf16x8 __attribute__((ext_vector_type(8)));
typedef __bf16 bf16x4 __attribute__((ext_vector_type(4)));
typedef float  f32x4  __attribute__((ext_vector_type(4)));

__device__ __forceinline__ void gl2lds16(const void* g, void* l) {
  __builtin_amdgcn_global_load_lds(
      (const __attribute__((address_space(1))) void*)g,
      (__attribute__((address_space(3))) void*)l, 16, 0, 0);
}

// swB slot(e,panel,kt,lane) = W[e][kt*32 + (lane>>4)*8 .. +8][panel*16 + (lane&15)]

// ---------------- prepass: W transpose fp32 -> bf16 swizzled (W-only now) ----------------
__global__ __launch_bounds__(256) void prepass_w(
    const float* __restrict__ W, __bf16* __restrict__ swB)
{
  __shared__ __align__(16) __bf16 Lt[64 * 72];
  const int t = threadIdx.x;
  int bid = blockIdx.x;
  int e = bid >> 8, r = bid & 255;
  int k0 = (r >> 4) * 64, n0 = (r & 15) * 64;
  const float* Wp = W + (size_t)e * KDIM * NDIM;
  int rr0 = t >> 4, c4 = t & 15;
#pragma unroll
  for (int p = 0; p < 4; ++p) {
    int kk = rr0 + p * 16;
    float4 v = *(const float4*)(Wp + (size_t)(k0 + kk) * NDIM + n0 + c4 * 4);
    Lt[(c4 * 4 + 0) * 72 + kk] = (__bf16)v.x;
    Lt[(c4 * 4 + 1) * 72 + kk] = (__bf16)v.y;
    Lt[(c4 * 4 + 2) * 72 + kk] = (__bf16)v.z;
    Lt[(c4 * 4 + 3) * 72 + kk] = (__bf16)v.w;
  }
  __syncthreads();
#pragma unroll
  for (int q = 0; q < 2; ++q) {
    int slot = q * 256 + t;
    int lane = slot & 63, grp = slot >> 6;
    int np = grp & 3, kt2 = grp >> 2;
    int nl = np * 16 + (lane & 15);
    int kl = kt2 * 32 + ((lane >> 4) << 3);
    bf16x8 v = *(const bf16x8*)(Lt + nl * 72 + kl);
    int panel = (n0 >> 4) + np;
    int ktg = (k0 >> 5) + kt2;
    size_t sg = (((size_t)e * 64 + panel) * 32 + ktg) * 64 + lane;
    *(bf16x8*)(swB + sg * 8) = v;
  }
}

// ---------------- GEMM: A reg-staged from fp32 x (T14 split), B via gl2lds ----------------
// LDS buf layout per stage: A slots 0..511 (panel*64 + kgrp*16 + rowlane, 8 bf16 each),
//                           B slots 512..1023.
// Sync protocol per iter kt (audited):
//   issue order: B(kt+1) [prev iter, oldest] | x(kt+1) x4 | B(kt+2) x2 [newest]
//   top:  vmcnt(2) [B(kt) retired], lgkmcnt(0) [A writes visible], s_barrier -> slice kt ready
//   then: issue x(kt+1), stage B(kt+2), sched_barrier(0), MFMA cluster (setprio 1)
//   end:  vmcnt(2) [retires x(kt+1); B(kt+2) stays in flight; never 0 mid-loop], ds_write A(kt+1)
// WAR safety: write targets buf[(kt+1)%3]; last readers (compute kt-2) finished before
// barrier(kt-1) < write time. gl2lds targets buf[(kt+2)%3]=(kt-1)%3; readers done at barrier(kt).
__global__ __launch_bounds__(256, 3) void moe_gemm_lds(
    const float* __restrict__ x, const __bf16* __restrict__ swB,
    const int* __restrict__ gs, const float* __restrict__ bias,
    float* __restrict__ out)
{
  __shared__ __align__(16) __bf16 buf[3][8192];   // 3 x 16 KB

  int y = blockIdx.y;
  int e = 0, tile0 = 0, lo = 0, hi = 0, found = 0, off = 0;
#pragma unroll
  for (int i = 0; i < NEXP; ++i) {
    int g = gs[i];
    int first = off >> 7;
    int cnt = (g > 0) ? (((off + g - 1) >> 7) - first + 1) : 0;
    if (!found) {
      if (y < cnt) {
        found = 1; e = i; tile0 = (first + y) << 7;
        lo = max(tile0, off); hi = min(tile0 + 128, off + g);
      } else y -= cnt;
    }
    off += g;
  }
  if (!found) return;                       // block-uniform: no barrier mismatch
  const int n0 = blockIdx.x * 128;

  const int t = threadIdx.x, lane = t & 63, wv = t >> 6;
  const int wm = wv & 1, wn = wv >> 1, lm = lane & 15, lg = lane >> 4;

  // B staging sources (panel stride = 32 kt * 512 elems = 16384)
  const __bf16* gB0 = swB + (size_t)(e * 64 + (n0 >> 4) + wv) * 16384 + lane * 8;
  const __bf16* gB1 = swB + (size_t)(e * 64 + (n0 >> 4) + 4 + wv) * 16384 + lane * 8;

  auto stage_B = [&](int kt, int sb) {
    __bf16* l = &buf[sb][0];
    const int ko = kt * 512;
    gl2lds16(gB0 + ko, l + (size_t)(512 + wv * 64) * 8);       // B panel wv
    gl2lds16(gB1 + ko, l + (size_t)(768 + wv * 64) * 8);       // B panel 4+wv
  };

  // A register staging: thread t, pass i: row r = i*32 + (t>>3), float4-col c = t&7
  //   -> slot(panel = r>>4, slotlane = (c>>1)*16 + (r&15)), elems (c&1)*4..+4
  //   global: 8 lanes/row x 128B contiguous; LDS write: b64, 16 banks, 4-way (free-ish)
  const float* xbase = x + (size_t)(tile0 + (t >> 3)) * KDIM + (t & 7) * 4;
  const int abase = (((t >> 7) * 64 + ((t & 7) >> 1) * 16 + ((t >> 3) & 15)) << 3) + (t & 1) * 4;

  auto issue_x = [&](int kt, float4* R) {
#pragma unroll
    for (int i = 0; i < 4; ++i)
      R[i] = *(const float4*)(xbase + (size_t)i * 32 * KDIM + kt * 32);
  };
  auto write_A = [&](int sb, const float4* R) {
    __bf16* l = &buf[sb][0] + abase;
#pragma unroll
    for (int i = 0; i < 4; ++i) {
      bf16x4 b;
      b[0] = (__bf16)R[i].x; b[1] = (__bf16)R[i].y;
      b[2] = (__bf16)R[i].z; b[3] = (__bf16)R[i].w;
      *(bf16x4*)(l + i * 1024) = b;   // panel stride 2 panels = 1024 elems
    }
  };

  f32x4 acc[4][4] = {};
  auto compute = [&](const __bf16* l) {
    bf16x8 aF[4], bF[4];
#pragma unroll
    for (int i = 0; i < 4; ++i)
      aF[i] = *(const bf16x8*)(l + (size_t)((wm * 4 + i) * 64 + lane) * 8);
#pragma unroll
    for (int j = 0; j < 4; ++j)
      bF[j] = *(const bf16x8*)(l + 4096 + (size_t)((wn * 4 + j) * 64 + lane) * 8);
#pragma unroll
    for (int i = 0; i < 4; ++i)
#pragma unroll
      for (int j = 0; j < 4; ++j)
        acc[i][j] = __builtin_amdgcn_mfma_f32_16x16x32_bf16(aF[i], bF[j], acc[i][j], 0, 0, 0);
  };

  // prologue: x(0) oldest, then B(0), B(1) -> vmcnt(4) retires exactly x(0)
  {
    float4 R0[4];
    issue_x(0, R0);
    stage_B(0, 0);
    stage_B(1, 1);
    asm volatile("s_waitcnt vmcnt(4)" ::: "memory");
    write_A(0, R0);
  }

#pragma unroll 1
  for (int kt = 0; kt < NT; ++kt) {
    asm volatile("s_waitcnt vmcnt(2)" ::: "memory");    // B(kt) landed (no-op in steady state)
    asm volatile("s_waitcnt lgkmcnt(0)" ::: "memory");  // A(kt) ds_writes visible
    asm volatile("s_barrier" ::: "memory");             // slice kt published

    float4 R[4];
    const bool havex = (kt + 1 < NT);
    if (havex) issue_x(kt + 1, R);                      // VMEM issued before MFMA burst
    if (kt + 2 < NT) stage_B(kt + 2, (kt + 2) % 3);
    __builtin_amdgcn_sched_barrier(0);                  // pin loads above the MFMA cluster

    __builtin_amdgcn_s_setprio(1);
    compute(&buf[kt % 3][0]);
    __builtin_amdgcn_s_setprio(0);

    if (havex) {
      if (kt + 2 < NT) asm volatile("s_waitcnt vmcnt(2)" ::: "memory");  // x done, B(kt+2) in flight
      else             asm volatile("s_waitcnt vmcnt(0)" ::: "memory");  // tail: nothing to keep
      write_A((kt + 1) % 3, R);
    }
  }

  float bj[4];
#pragma unroll
  for (int j = 0; j < 4; ++j) bj[j] = bias[e * NDIM + n0 + wn * 64 + j * 16 + lm];
#pragma unroll
  for (int i = 0; i < 4; ++i)
#pragma unroll
    for (int r = 0; r < 4; ++r) {
      int rabs = tile0 + wm * 64 + i * 16 + lg * 4 + r;   // C/D: row = quad*4 + reg
      if (rabs >= lo && rabs < hi) {
#pragma unroll
        for (int j = 0; j < 4; ++j)
          out[(size_t)rabs * NDIM + n0 + wn * 64 + j * 16 + lm] = acc[i][j][r] + bj[j];
      }
    }
}

// ---------------- fallback (fp32 in-loop conversion) for small ws ----------------
#define LDA 40
__global__ __launch_bounds__(256) void moe_gemm_kernel(
    const float* __restrict__ x, const int* __restrict__ gs,
    const float* __restrict__ W, const float* __restrict__ bias,
    float* __restrict__ out)
{
  __shared__ __bf16 Al[128 * LDA];
  __shared__ __bf16 Bl[128 * LDA];
  const int e = blockIdx.z, mt = blockIdx.y, nt = blockIdx.x;
  int off = 0;
#pragma unroll
  for (int i = 0; i < NEXP; ++i) { int g = gs[i]; if (i < e) off += g; }
  const int ge = gs[e];
  const int m0 = mt * 128;
  if (m0 >= ge) return;
  const int rows = min(128, ge - m0);
  const int row0 = off + m0;
  const int n0 = nt * 128;
  const int t = threadIdx.x, lane = t & 63, wv = t >> 6;
  const int wm = wv & 1, wn = wv >> 1, lm = lane & 15, lg = lane >> 4;
  const int am = t >> 3, kq = t & 7, nb = t & 127, kh = t >> 7;
  float4 aReg[4]; float bReg[16];
  const float* Wp = W + (size_t)e * KDIM * NDIM + n0 + nb;
  auto load_tile = [&](int kt) {
#pragma unroll
    for (int p = 0; p < 4; ++p) {
      int r = am + 32 * p;
      if (r < rows) aReg[p] = *(const float4*)(x + (size_t)(row0 + r) * KDIM + kt * 32 + kq * 4);
      else aReg[p] = make_float4(0.f, 0.f, 0.f, 0.f);
    }
    const float* wp = Wp + (size_t)(kt * 32 + kh * 16) * NDIM;
#pragma unroll
    for (int j = 0; j < 16; ++j) bReg[j] = wp[(size_t)j * NDIM];
  };
  auto store_tile = [&]() {
#pragma unroll
    for (int p = 0; p < 4; ++p) {
      bf16x4 v;
      v[0] = (__bf16)aReg[p].x; v[1] = (__bf16)aReg[p].y;
      v[2] = (__bf16)aReg[p].z; v[3] = (__bf16)aReg[p].w;
      *(bf16x4*)(Al + (am + 32 * p) * LDA + kq * 4) = v;
    }
    bf16x8 b0, b1;
#pragma unroll
    for (int j = 0; j < 8; ++j) { b0[j] = (__bf16)bReg[j]; b1[j] = (__bf16)bReg[8 + j]; }
    *(bf16x8*)(Bl + nb * LDA + kh * 16) = b0;
    *(bf16x8*)(Bl + nb * LDA + kh * 16 + 8) = b1;
  };
  f32x4 acc[4][4] = {};
  load_tile(0);
#pragma unroll 1
  for (int kt = 0; kt < KDIM / 32; ++kt) {
    __syncthreads();
    store_tile();
    __syncthreads();
    if (kt + 1 < KDIM / 32) load_tile(kt + 1);
    bf16x8 af[4], bfr[4];
#pragma unroll
    for (int i = 0; i < 4; ++i)
      af[i] = *(const bf16x8*)(Al + (wm * 64 + i * 16 + lm) * LDA + lg * 8);
#pragma unroll
    for (int j = 0; j < 4; ++j)
      bfr[j] = *(const bf16x8*)(Bl + (wn * 64 + j * 16 + lm) * LDA + lg * 8);
#pragma unroll
    for (int i = 0; i < 4; ++i)
#pragma unroll
      for (int j = 0; j < 4; ++j)
        acc[i][j] = __builtin_amdgcn_mfma_f32_16x16x32_bf16(af[i], bfr[j], acc[i][j], 0, 0, 0);
  }
  float bj[4];
#pragma unroll
  for (int j = 0; j < 4; ++j) bj[j] = bias[e * NDIM + n0 + wn * 64 + j * 16 + lm];
#pragma unroll
  for (int i = 0; i < 4; ++i)
#pragma unroll
    for (int r = 0; r < 4; ++r) {
      int rr = wm * 64 + i * 16 + lg * 4 + r;
      if (rr < rows) {
#pragma unroll
        for (int j = 0; j < 4; ++j)
          out[(size_t)(row0 + rr) * NDIM + n0 + wn * 64 + j * 16 + lm] = acc[i][j][r] + bj[j];
      }
    }
}

extern "C" void kernel_launch(void* const* d_in, const int* in_sizes, int n_in,
                              void* d_out, int out_size, void* d_ws, size_t ws_size,
                              hipStream_t stream) {
  const float* x    = (const float*)d_in[0];
  const int*   gs   = (const int*)d_in[1];
  const float* W    = (const float*)d_in[2];
  const float* bias = (const float*)d_in[3];
  float*       out  = (float*)d_out;

  const size_t swB_bytes = (size_t)NEXP * KDIM * NDIM * 2;
  if (ws_size >= swB_bytes) {
    __bf16* swB = (__bf16*)d_ws;
    prepass_w<<<dim3(2048), 256, 0, stream>>>(W, swB);
    // x = n-tile (8): linear id % 8 == n-tile -> each XCD keeps its B n-column
    // (8 experts x 256 KB = 2 MB) L2-resident.
    moe_gemm_lds<<<dim3(NDIM / 128, 72), 256, 0, stream>>>(x, swB, gs, bias, out);
  } else {
    moe_gemm_kernel<<<dim3(NDIM / 128, TTOK / 128, NEXP), 256, 0, stream>>>(x, gs, W, bias, out);
  }
}

// Round 2
// 137.571 us; speedup vs baseline: 1.0781x; 1.0781x over previous
//
#include <hip/hip_runtime.h>
#include <hip/hip_bf16.h>

#define KDIM 1024
#define NDIM 1024
#define NEXP 8
#define TTOK 8192
#define NT (KDIM / 32)

typedef __bf16 bf16x8 __attribute__((ext_vector_type(8)));
typedef __bf16 bf16x4 __attribute__((ext_vector_type(4)));
typedef float  f32x4  __attribute__((ext_vector_type(4)));

__device__ __forceinline__ void gl2lds16(const void* g, void* l) {
  __builtin_amdgcn_global_load_lds(
      (const __attribute__((address_space(1))) void*)g,
      (__attribute__((address_space(3))) void*)l, 16, 0, 0);
}

// Fragment-swizzled layouts (16B per lane-slot):
//   swA slot(panel,kt,lane) = x[panel*16 + (lane&15)][kt*32 + (lane>>4)*8 .. +8]
//   swB slot(e,panel,kt,lane) = W[e][kt*32 + (lane>>4)*8 .. +8][panel*16 + (lane&15)]

// ---------------- prepass: build swA (x fp32->bf16) and swB (W transpose) ----------------
__global__ __launch_bounds__(256) void prepass(
    const float* __restrict__ x, const float* __restrict__ W,
    __bf16* __restrict__ swA, __bf16* __restrict__ swB)
{
  __shared__ __align__(16) __bf16 Lt[64 * 72];
  const int t = threadIdx.x;
  if (blockIdx.x < 1024) {
#pragma unroll
    for (int p = 0; p < 4; ++p) {
      int s = blockIdx.x * 1024 + p * 256 + t;
      int lane = s & 63, kt = (s >> 6) & 31, panel = s >> 11;
      int row = panel * 16 + (lane & 15);
      int k0 = kt * 32 + ((lane >> 4) << 3);
      const float* xp = x + (size_t)row * KDIM + k0;
      float4 a = *(const float4*)xp;
      float4 b = *(const float4*)(xp + 4);
      bf16x8 v;
      v[0] = (__bf16)a.x; v[1] = (__bf16)a.y; v[2] = (__bf16)a.z; v[3] = (__bf16)a.w;
      v[4] = (__bf16)b.x; v[5] = (__bf16)b.y; v[6] = (__bf16)b.z; v[7] = (__bf16)b.w;
      *(bf16x8*)(swA + (size_t)s * 8) = v;
    }
  } else {
    int bid = blockIdx.x - 1024;
    int e = bid >> 8, r = bid & 255;
    int k0 = (r >> 4) * 64, n0 = (r & 15) * 64;
    const float* Wp = W + (size_t)e * KDIM * NDIM;
    int rr0 = t >> 4, c4 = t & 15;
#pragma unroll
    for (int p = 0; p < 4; ++p) {
      int kk = rr0 + p * 16;
      float4 v = *(const float4*)(Wp + (size_t)(k0 + kk) * NDIM + n0 + c4 * 4);
      Lt[(c4 * 4 + 0) * 72 + kk] = (__bf16)v.x;
      Lt[(c4 * 4 + 1) * 72 + kk] = (__bf16)v.y;
      Lt[(c4 * 4 + 2) * 72 + kk] = (__bf16)v.z;
      Lt[(c4 * 4 + 3) * 72 + kk] = (__bf16)v.w;
    }
    __syncthreads();
#pragma unroll
    for (int q = 0; q < 2; ++q) {
      int slot = q * 256 + t;
      int lane = slot & 63, grp = slot >> 6;
      int np = grp & 3, kt2 = grp >> 2;
      int nl = np * 16 + (lane & 15);
      int kl = kt2 * 32 + ((lane >> 4) << 3);
      bf16x8 v = *(const bf16x8*)(Lt + nl * 72 + kl);
      int panel = (n0 >> 4) + np;
      int ktg = (k0 >> 5) + kt2;
      size_t sg = (((size_t)e * 64 + panel) * 32 + ktg) * 64 + lane;
      *(bf16x8*)(swB + sg * 8) = v;
    }
  }
}

// ---------------- GEMM: 8-wave 128x128 tile, 3-stage pipeline, counted vmcnt ----------------
// Round-0 data path (swA + swB via global_load_lds) restored; the one change vs round-0
// is tile partitioning: 8 waves x (64x32 wave-tile) instead of 4 x (64x64).
//   - resident waves/CU: 3 blocks x 8 waves = 24 (vs 12) -> more TLP to hide the
//     vmcnt+barrier drain (m114: implicit wave-level overlap is what fills this structure)
//   - each wave stages exactly 1 A-panel + 1 B-panel per kt (2 gl2lds): steady-state
//     wait is vmcnt(2) (slice kt retired, kt+1 in flight), vmcnt(0) only at the tail.
// WAR safety (3 buffers): stage(kt+2) writes buf[(kt+2)%3] after barrier(kt); its last
// readers ran compute(kt-1) which precedes barrier(kt) in every wave's program order.
__global__ __launch_bounds__(512, 6) void moe_gemm_lds(
    const __bf16* __restrict__ swA, const __bf16* __restrict__ swB,
    const int* __restrict__ gs, const float* __restrict__ bias,
    float* __restrict__ out)
{
  __shared__ __align__(16) __bf16 buf[3][8192];   // 3 x 16 KB (A slots 0..511, B 512..1023)

  int y = blockIdx.y;
  int e = 0, tile0 = 0, lo = 0, hi = 0, found = 0, off = 0;
#pragma unroll
  for (int i = 0; i < NEXP; ++i) {
    int g = gs[i];
    int first = off >> 7;
    int cnt = (g > 0) ? (((off + g - 1) >> 7) - first + 1) : 0;
    if (!found) {
      if (y < cnt) {
        found = 1; e = i; tile0 = (first + y) << 7;
        lo = max(tile0, off); hi = min(tile0 + 128, off + g);
      } else y -= cnt;
    }
    off += g;
  }
  if (!found) return;                       // block-uniform: no barrier mismatch
  const int n0 = blockIdx.x * 128;

  const int t = threadIdx.x, lane = t & 63, wv = t >> 6;   // wv 0..7
  const int wm = wv & 1, wn = wv >> 1, lm = lane & 15, lg = lane >> 4;

  // staging sources: wave wv stages A panel wv and B panel wv
  // (panel stride = 32 kt * 512 elems = 16384; per-kt stride = 512 elems)
  const __bf16* gA = swA + (size_t)((tile0 >> 4) + wv) * 16384 + lane * 8;
  const __bf16* gB = swB + (size_t)(e * 64 + (n0 >> 4) + wv) * 16384 + lane * 8;

  auto stage = [&](int kt, int sb) {
    __bf16* l = &buf[sb][0];
    const int ko = kt * 512;
    gl2lds16(gA + ko, l + (size_t)(wv * 64) * 8);           // A panel wv   (slots 0..511)
    gl2lds16(gB + ko, l + (size_t)(512 + wv * 64) * 8);     // B panel wv   (slots 512..1023)
  };

  f32x4 acc[4][2] = {};
  auto compute = [&](const __bf16* l) {
    bf16x8 aF[4], bF[2];
#pragma unroll
    for (int i = 0; i < 4; ++i)
      aF[i] = *(const bf16x8*)(l + (size_t)((wm * 4 + i) * 64 + lane) * 8);
#pragma unroll
    for (int j = 0; j < 2; ++j)
      bF[j] = *(const bf16x8*)(l + 4096 + (size_t)((wn * 2 + j) * 64 + lane) * 8);
#pragma unroll
    for (int i = 0; i < 4; ++i)
#pragma unroll
      for (int j = 0; j < 2; ++j)
        acc[i][j] = __builtin_amdgcn_mfma_f32_16x16x32_bf16(aF[i], bF[j], acc[i][j], 0, 0, 0);
  };

  stage(0, 0);            // oldest 2 outstanding
  stage(1, 1);            // newest 2 outstanding
#pragma unroll 1
  for (int kt = 0; kt < NT - 1; ++kt) {
    // wait until <=2 outstanding: slice kt's 2 stages done; kt+1's stay in flight
    asm volatile("s_waitcnt vmcnt(2)" ::: "memory");
    asm volatile("s_barrier" ::: "memory");
    compute(&buf[kt % 3][0]);
    if (kt + 2 < NT) stage(kt + 2, (kt + 2) % 3);
  }
  asm volatile("s_waitcnt vmcnt(0)" ::: "memory");   // final slice: nothing left in flight
  asm volatile("s_barrier" ::: "memory");
  compute(&buf[(NT - 1) % 3][0]);

  float bj[2];
#pragma unroll
  for (int j = 0; j < 2; ++j) bj[j] = bias[e * NDIM + n0 + wn * 32 + j * 16 + lm];
#pragma unroll
  for (int i = 0; i < 4; ++i)
#pragma unroll
    for (int r = 0; r < 4; ++r) {
      int rabs = tile0 + wm * 64 + i * 16 + lg * 4 + r;   // C/D: row = quad*4 + reg
      if (rabs >= lo && rabs < hi) {
#pragma unroll
        for (int j = 0; j < 2; ++j)
          out[(size_t)rabs * NDIM + n0 + wn * 32 + j * 16 + lm] = acc[i][j][r] + bj[j];
      }
    }
}

// ---------------- fallback (fp32 in-loop conversion) for small ws ----------------
#define LDA 40
__global__ __launch_bounds__(256) void moe_gemm_kernel(
    const float* __restrict__ x, const int* __restrict__ gs,
    const float* __restrict__ W, const float* __restrict__ bias,
    float* __restrict__ out)
{
  __shared__ __bf16 Al[128 * LDA];
  __shared__ __bf16 Bl[128 * LDA];
  const int e = blockIdx.z, mt = blockIdx.y, nt = blockIdx.x;
  int off = 0;
#pragma unroll
  for (int i = 0; i < NEXP; ++i) { int g = gs[i]; if (i < e) off += g; }
  const int ge = gs[e];
  const int m0 = mt * 128;
  if (m0 >= ge) return;
  const int rows = min(128, ge - m0);
  const int row0 = off + m0;
  const int n0 = nt * 128;
  const int t = threadIdx.x, lane = t & 63, wv = t >> 6;
  const int wm = wv & 1, wn = wv >> 1, lm = lane & 15, lg = lane >> 4;
  const int am = t >> 3, kq = t & 7, nb = t & 127, kh = t >> 7;
  float4 aReg[4]; float bReg[16];
  const float* Wp = W + (size_t)e * KDIM * NDIM + n0 + nb;
  auto load_tile = [&](int kt) {
#pragma unroll
    for (int p = 0; p < 4; ++p) {
      int r = am + 32 * p;
      if (r < rows) aReg[p] = *(const float4*)(x + (size_t)(row0 + r) * KDIM + kt * 32 + kq * 4);
      else aReg[p] = make_float4(0.f, 0.f, 0.f, 0.f);
    }
    const float* wp = Wp + (size_t)(kt * 32 + kh * 16) * NDIM;
#pragma unroll
    for (int j = 0; j < 16; ++j) bReg[j] = wp[(size_t)j * NDIM];
  };
  auto store_tile = [&]() {
#pragma unroll
    for (int p = 0; p < 4; ++p) {
      bf16x4 v;
      v[0] = (__bf16)aReg[p].x; v[1] = (__bf16)aReg[p].y;
      v[2] = (__bf16)aReg[p].z; v[3] = (__bf16)aReg[p].w;
      *(bf16x4*)(Al + (am + 32 * p) * LDA + kq * 4) = v;
    }
    bf16x8 b0, b1;
#pragma unroll
    for (int j = 0; j < 8; ++j) { b0[j] = (__bf16)bReg[j]; b1[j] = (__bf16)bReg[8 + j]; }
    *(bf16x8*)(Bl + nb * LDA + kh * 16) = b0;
    *(bf16x8*)(Bl + nb * LDA + kh * 16 + 8) = b1;
  };
  f32x4 acc[4][4] = {};
  load_tile(0);
#pragma unroll 1
  for (int kt = 0; kt < KDIM / 32; ++kt) {
    __syncthreads();
    store_tile();
    __syncthreads();
    if (kt + 1 < KDIM / 32) load_tile(kt + 1);
    bf16x8 af[4], bfr[4];
#pragma unroll
    for (int i = 0; i < 4; ++i)
      af[i] = *(const bf16x8*)(Al + (wm * 64 + i * 16 + lm) * LDA + lg * 8);
#pragma unroll
    for (int j = 0; j < 4; ++j)
      bfr[j] = *(const bf16x8*)(Bl + (wn * 64 + j * 16 + lm) * LDA + lg * 8);
#pragma unroll
    for (int i = 0; i < 4; ++i)
#pragma unroll
      for (int j = 0; j < 4; ++j)
        acc[i][j] = __builtin_amdgcn_mfma_f32_16x16x32_bf16(af[i], bfr[j], acc[i][j], 0, 0, 0);
  }
  float bj[4];
#pragma unroll
  for (int j = 0; j < 4; ++j) bj[j] = bias[e * NDIM + n0 + wn * 64 + j * 16 + lm];
#pragma unroll
  for (int i = 0; i < 4; ++i)
#pragma unroll
    for (int r = 0; r < 4; ++r) {
      int rr = wm * 64 + i * 16 + lg * 4 + r;
      if (rr < rows) {
#pragma unroll
        for (int j = 0; j < 4; ++j)
          out[(size_t)(row0 + rr) * NDIM + n0 + wn * 64 + j * 16 + lm] = acc[i][j][r] + bj[j];
      }
    }
}

extern "C" void kernel_launch(void* const* d_in, const int* in_sizes, int n_in,
                              void* d_out, int out_size, void* d_ws, size_t ws_size,
                              hipStream_t stream) {
  const float* x    = (const float*)d_in[0];
  const int*   gs   = (const int*)d_in[1];
  const float* W    = (const float*)d_in[2];
  const float* bias = (const float*)d_in[3];
  float*       out  = (float*)d_out;

  const size_t swA_bytes = (size_t)TTOK * KDIM * 2;
  const size_t swB_bytes = (size_t)NEXP * KDIM * NDIM * 2;
  if (ws_size >= swA_bytes + swB_bytes) {
    __bf16* swA = (__bf16*)d_ws;
    __bf16* swB = (__bf16*)((char*)d_ws + swA_bytes);
    prepass<<<dim3(1024 + 2048), 256, 0, stream>>>(x, W, swA, swB);
    // x = n-tile (8): linear id % 8 == n-tile -> each XCD keeps its B n-column
    // (8 experts x 256 KB = 2 MB) L2-resident.
    moe_gemm_lds<<<dim3(NDIM / 128, 72), 512, 0, stream>>>(swA, swB, gs, bias, out);
  } else {
    moe_gemm_kernel<<<dim3(NDIM / 128, TTOK / 128, NEXP), 256, 0, stream>>>(x, gs, W, bias, out);
  }
}

// Round 3
// 132.482 us; speedup vs baseline: 1.1195x; 1.0384x over previous
//
#include <hip/hip_runtime.h>
#include <hip/hip_bf16.h>

#define KDIM 1024
#define NDIM 1024
#define NEXP 8
#define TTOK 8192
#define NT (KDIM / 32)

typedef __bf16 bf16x8 __attribute__((ext_vector_type(8)));
typedef __bf16 bf16x4 __attribute__((ext_vector_type(4)));
typedef float  f32x4  __attribute__((ext_vector_type(4)));

__device__ __forceinline__ void gl2lds16(const void* g, void* l) {
  __builtin_amdgcn_global_load_lds(
      (const __attribute__((address_space(1))) void*)g,
      (__attribute__((address_space(3))) void*)l, 16, 0, 0);
}

// Fragment-swizzled layouts (16B per lane-slot):
//   swA slot(panel,kt,lane) = x[panel*16 + (lane&15)][kt*32 + (lane>>4)*8 .. +8]
//   swB slot(e,panel,kt,lane) = W[e][kt*32 + (lane>>4)*8 .. +8][panel*16 + (lane&15)]

// ---------------- prepass: build swA (x fp32->bf16) and swB (W transpose) ----------------
__global__ __launch_bounds__(256) void prepass(
    const float* __restrict__ x, const float* __restrict__ W,
    __bf16* __restrict__ swA, __bf16* __restrict__ swB)
{
  __shared__ __align__(16) __bf16 Lt[64 * 72];
  const int t = threadIdx.x;
  if (blockIdx.x < 1024) {
#pragma unroll
    for (int p = 0; p < 4; ++p) {
      int s = blockIdx.x * 1024 + p * 256 + t;
      int lane = s & 63, kt = (s >> 6) & 31, panel = s >> 11;
      int row = panel * 16 + (lane & 15);
      int k0 = kt * 32 + ((lane >> 4) << 3);
      const float* xp = x + (size_t)row * KDIM + k0;
      float4 a = *(const float4*)xp;
      float4 b = *(const float4*)(xp + 4);
      bf16x8 v;
      v[0] = (__bf16)a.x; v[1] = (__bf16)a.y; v[2] = (__bf16)a.z; v[3] = (__bf16)a.w;
      v[4] = (__bf16)b.x; v[5] = (__bf16)b.y; v[6] = (__bf16)b.z; v[7] = (__bf16)b.w;
      *(bf16x8*)(swA + (size_t)s * 8) = v;
    }
  } else {
    int bid = blockIdx.x - 1024;
    int e = bid >> 8, r = bid & 255;
    int k0 = (r >> 4) * 64, n0 = (r & 15) * 64;
    const float* Wp = W + (size_t)e * KDIM * NDIM;
    int rr0 = t >> 4, c4 = t & 15;
#pragma unroll
    for (int p = 0; p < 4; ++p) {
      int kk = rr0 + p * 16;
      float4 v = *(const float4*)(Wp + (size_t)(k0 + kk) * NDIM + n0 + c4 * 4);
      Lt[(c4 * 4 + 0) * 72 + kk] = (__bf16)v.x;
      Lt[(c4 * 4 + 1) * 72 + kk] = (__bf16)v.y;
      Lt[(c4 * 4 + 2) * 72 + kk] = (__bf16)v.z;
      Lt[(c4 * 4 + 3) * 72 + kk] = (__bf16)v.w;
    }
    __syncthreads();
#pragma unroll
    for (int q = 0; q < 2; ++q) {
      int slot = q * 256 + t;
      int lane = slot & 63, grp = slot >> 6;
      int np = grp & 3, kt2 = grp >> 2;
      int nl = np * 16 + (lane & 15);
      int kl = kt2 * 32 + ((lane >> 4) << 3);
      bf16x8 v = *(const bf16x8*)(Lt + nl * 72 + kl);
      int panel = (n0 >> 4) + np;
      int ktg = (k0 >> 5) + kt2;
      size_t sg = (((size_t)e * 64 + panel) * 32 + ktg) * 64 + lane;
      *(bf16x8*)(swB + sg * 8) = v;
    }
  }
}

// ---------------- GEMM: round-0 4-wave structure + XCD m-range ownership ----------------
// Block mapping (1D grid 576, XCD = linear id % 8 heuristic):
//   xcd = b&7, i = b>>3 (0..71), mt = xcd*9 + i%9, nt = i/9
// -> each XCD owns 9 CONTIGUOUS m-tiles (2.25 MB swA slice, L2-resident, HBM-read once)
//    x all 8 n-tiles; B slices for the 1-2 experts overlapping the m-range (~0.5 MB live
//    per n-pass). GEMM HBM traffic drops ~176 MB -> ~70 MB (A no longer re-fetched 8x).
// Pipeline identical to round-0: 3-stage LDS, per-wave vmcnt(4) counted wait + raw
// s_barrier; 4 gl2lds per wave per kt (A panels {wv,4+wv}, B panels {wv,4+wv}).
// WAR safety: stage(kt+2) after barrier(kt); buf[(kt+2)%3]'s last readers ran
// compute(kt-1) which precedes barrier(kt) in every wave's program order.
__global__ __launch_bounds__(256, 3) void moe_gemm_lds(
    const __bf16* __restrict__ swA, const __bf16* __restrict__ swB,
    const int* __restrict__ gs, const float* __restrict__ bias,
    float* __restrict__ out)
{
  __shared__ __align__(16) __bf16 buf[3][8192];   // 3 x 16 KB (A slots 0..511, B 512..1023)

  const int b = blockIdx.x;
  const int xcd = b & 7, bi = b >> 3;
  int y = xcd * 9 + bi % 9;           // global m-tile index (<= 71 always used)
  const int nt = bi / 9;

  int e = 0, tile0 = 0, lo = 0, hi = 0, found = 0, off = 0;
#pragma unroll
  for (int i = 0; i < NEXP; ++i) {
    int g = gs[i];
    int first = off >> 7;
    int cnt = (g > 0) ? (((off + g - 1) >> 7) - first + 1) : 0;
    if (!found) {
      if (y < cnt) {
        found = 1; e = i; tile0 = (first + y) << 7;
        lo = max(tile0, off); hi = min(tile0 + 128, off + g);
      } else y -= cnt;
    }
    off += g;
  }
  if (!found) return;                       // block-uniform: no barrier mismatch
  const int n0 = nt * 128;

  const int t = threadIdx.x, lane = t & 63, wv = t >> 6;
  const int wm = wv & 1, wn = wv >> 1, lm = lane & 15, lg = lane >> 4;

  // staging sources: wave wv stages A panels {wv, 4+wv} and B panels {wv, 4+wv}
  // (panel stride = 32 kt * 512 elems = 16384; per-kt stride = 512 elems)
  const __bf16* gA0 = swA + (size_t)((tile0 >> 4) + wv) * 16384 + lane * 8;
  const __bf16* gA1 = swA + (size_t)((tile0 >> 4) + 4 + wv) * 16384 + lane * 8;
  const __bf16* gB0 = swB + (size_t)(e * 64 + (n0 >> 4) + wv) * 16384 + lane * 8;
  const __bf16* gB1 = swB + (size_t)(e * 64 + (n0 >> 4) + 4 + wv) * 16384 + lane * 8;

  auto stage = [&](int kt, int sb) {
    __bf16* l = &buf[sb][0];
    const int ko = kt * 512;
    gl2lds16(gA0 + ko, l + (size_t)(0 * 256 + wv * 64) * 8);   // A panel wv
    gl2lds16(gA1 + ko, l + (size_t)(1 * 256 + wv * 64) * 8);   // A panel 4+wv
    gl2lds16(gB0 + ko, l + (size_t)(2 * 256 + wv * 64) * 8);   // B panel wv
    gl2lds16(gB1 + ko, l + (size_t)(3 * 256 + wv * 64) * 8);   // B panel 4+wv
  };

  f32x4 acc[4][4] = {};
  auto compute = [&](const __bf16* l) {
    bf16x8 aF[4], bF[4];
#pragma unroll
    for (int i = 0; i < 4; ++i)
      aF[i] = *(const bf16x8*)(l + (size_t)((wm * 4 + i) * 64 + lane) * 8);
#pragma unroll
    for (int j = 0; j < 4; ++j)
      bF[j] = *(const bf16x8*)(l + 4096 + (size_t)((wn * 4 + j) * 64 + lane) * 8);
#pragma unroll
    for (int i = 0; i < 4; ++i)
#pragma unroll
      for (int j = 0; j < 4; ++j)
        acc[i][j] = __builtin_amdgcn_mfma_f32_16x16x32_bf16(aF[i], bF[j], acc[i][j], 0, 0, 0);
  };

  stage(0, 0);            // oldest 4 outstanding
  stage(1, 1);            // newest 4 outstanding
#pragma unroll 1
  for (int kt = 0; kt < NT - 1; ++kt) {
    // wait until <=4 outstanding: slice kt's 4 stages done; kt+1's stay in flight
    asm volatile("s_waitcnt vmcnt(4)" ::: "memory");
    asm volatile("s_barrier" ::: "memory");
    compute(&buf[kt % 3][0]);
    if (kt + 2 < NT) stage(kt + 2, (kt + 2) % 3);
  }
  asm volatile("s_waitcnt vmcnt(0)" ::: "memory");   // final slice: nothing left in flight
  asm volatile("s_barrier" ::: "memory");
  compute(&buf[(NT - 1) % 3][0]);

  float bj[4];
#pragma unroll
  for (int j = 0; j < 4; ++j) bj[j] = bias[e * NDIM + n0 + wn * 64 + j * 16 + lm];
#pragma unroll
  for (int i = 0; i < 4; ++i)
#pragma unroll
    for (int r = 0; r < 4; ++r) {
      int rabs = tile0 + wm * 64 + i * 16 + lg * 4 + r;   // C/D: row = quad*4 + reg
      if (rabs >= lo && rabs < hi) {
#pragma unroll
        for (int j = 0; j < 4; ++j)
          out[(size_t)rabs * NDIM + n0 + wn * 64 + j * 16 + lm] = acc[i][j][r] + bj[j];
      }
    }
}

// ---------------- fallback (fp32 in-loop conversion) for small ws ----------------
#define LDA 40
__global__ __launch_bounds__(256) void moe_gemm_kernel(
    const float* __restrict__ x, const int* __restrict__ gs,
    const float* __restrict__ W, const float* __restrict__ bias,
    float* __restrict__ out)
{
  __shared__ __bf16 Al[128 * LDA];
  __shared__ __bf16 Bl[128 * LDA];
  const int e = blockIdx.z, mt = blockIdx.y, nt = blockIdx.x;
  int off = 0;
#pragma unroll
  for (int i = 0; i < NEXP; ++i) { int g = gs[i]; if (i < e) off += g; }
  const int ge = gs[e];
  const int m0 = mt * 128;
  if (m0 >= ge) return;
  const int rows = min(128, ge - m0);
  const int row0 = off + m0;
  const int n0 = nt * 128;
  const int t = threadIdx.x, lane = t & 63, wv = t >> 6;
  const int wm = wv & 1, wn = wv >> 1, lm = lane & 15, lg = lane >> 4;
  const int am = t >> 3, kq = t & 7, nb = t & 127, kh = t >> 7;
  float4 aReg[4]; float bReg[16];
  const float* Wp = W + (size_t)e * KDIM * NDIM + n0 + nb;
  auto load_tile = [&](int kt) {
#pragma unroll
    for (int p = 0; p < 4; ++p) {
      int r = am + 32 * p;
      if (r < rows) aReg[p] = *(const float4*)(x + (size_t)(row0 + r) * KDIM + kt * 32 + kq * 4);
      else aReg[p] = make_float4(0.f, 0.f, 0.f, 0.f);
    }
    const float* wp = Wp + (size_t)(kt * 32 + kh * 16) * NDIM;
#pragma unroll
    for (int j = 0; j < 16; ++j) bReg[j] = wp[(size_t)j * NDIM];
  };
  auto store_tile = [&]() {
#pragma unroll
    for (int p = 0; p < 4; ++p) {
      bf16x4 v;
      v[0] = (__bf16)aReg[p].x; v[1] = (__bf16)aReg[p].y;
      v[2] = (__bf16)aReg[p].z; v[3] = (__bf16)aReg[p].w;
      *(bf16x4*)(Al + (am + 32 * p) * LDA + kq * 4) = v;
    }
    bf16x8 b0, b1;
#pragma unroll
    for (int j = 0; j < 8; ++j) { b0[j] = (__bf16)bReg[j]; b1[j] = (__bf16)bReg[8 + j]; }
    *(bf16x8*)(Bl + nb * LDA + kh * 16) = b0;
    *(bf16x8*)(Bl + nb * LDA + kh * 16 + 8) = b1;
  };
  f32x4 acc[4][4] = {};
  load_tile(0);
#pragma unroll 1
  for (int kt = 0; kt < KDIM / 32; ++kt) {
    __syncthreads();
    store_tile();
    __syncthreads();
    if (kt + 1 < KDIM / 32) load_tile(kt + 1);
    bf16x8 af[4], bfr[4];
#pragma unroll
    for (int i = 0; i < 4; ++i)
      af[i] = *(const bf16x8*)(Al + (wm * 64 + i * 16 + lm) * LDA + lg * 8);
#pragma unroll
    for (int j = 0; j < 4; ++j)
      bfr[j] = *(const bf16x8*)(Bl + (wn * 64 + j * 16 + lm) * LDA + lg * 8);
#pragma unroll
    for (int i = 0; i < 4; ++i)
#pragma unroll
      for (int j = 0; j < 4; ++j)
        acc[i][j] = __builtin_amdgcn_mfma_f32_16x16x32_bf16(af[i], bfr[j], acc[i][j], 0, 0, 0);
  }
  float bj[4];
#pragma unroll
  for (int j = 0; j < 4; ++j) bj[j] = bias[e * NDIM + n0 + wn * 64 + j * 16 + lm];
#pragma unroll
  for (int i = 0; i < 4; ++i)
#pragma unroll
    for (int r = 0; r < 4; ++r) {
      int rr = wm * 64 + i * 16 + lg * 4 + r;
      if (rr < rows) {
#pragma unroll
        for (int j = 0; j < 4; ++j)
          out[(size_t)(row0 + rr) * NDIM + n0 + wn * 64 + j * 16 + lm] = acc[i][j][r] + bj[j];
      }
    }
}

extern "C" void kernel_launch(void* const* d_in, const int* in_sizes, int n_in,
                              void* d_out, int out_size, void* d_ws, size_t ws_size,
                              hipStream_t stream) {
  const float* x    = (const float*)d_in[0];
  const int*   gs   = (const int*)d_in[1];
  const float* W    = (const float*)d_in[2];
  const float* bias = (const float*)d_in[3];
  float*       out  = (float*)d_out;

  const size_t swA_bytes = (size_t)TTOK * KDIM * 2;
  const size_t swB_bytes = (size_t)NEXP * KDIM * NDIM * 2;
  if (ws_size >= swA_bytes + swB_bytes) {
    __bf16* swA = (__bf16*)d_ws;
    __bf16* swB = (__bf16*)((char*)d_ws + swA_bytes);
    prepass<<<dim3(1024 + 2048), 256, 0, stream>>>(x, W, swA, swB);
    // 1D grid, XCD-contiguous m-ranges: xcd=b&7 owns m-tiles [9*xcd, 9*xcd+9) x all n.
    moe_gemm_lds<<<dim3(576), 256, 0, stream>>>(swA, swB, gs, bias, out);
  } else {
    moe_gemm_kernel<<<dim3(NDIM / 128, TTOK / 128, NEXP), 256, 0, stream>>>(x, gs, W, bias, out);
  }
}